// Round 11
// baseline (116.220 us; speedup 1.0000x reference)
//
#include <hip/hip_runtime.h>

#define B_    4
#define CIN_  128
#define COUT_ 128
#define EPSF  1e-8f

typedef short  short8  __attribute__((ext_vector_type(8)));
typedef unsigned short ushort8 __attribute__((ext_vector_type(8)));
typedef float  f32x16  __attribute__((ext_vector_type(16)));

__device__ __forceinline__ unsigned short f2bf(float f) {
    union { float f; unsigned int u; } v; v.f = f;
    unsigned int r = (v.u + 0x7fffu + ((v.u >> 16) & 1u)) >> 16;
    return (unsigned short)r;
}

// ---------- fused: weights -> fragment-ordered bf16  AND  d[b,co] scales ----------
// blocks 0..1727: wtf transform. blocks 1728..1855: dscale for co = bx-1728.
// wtf layout: [ko 27][cot 4][cich 8][lane 64][e 8]
__global__ __launch_bounds__(256) void wt_scale_kernel(const float* __restrict__ w,
                                                       const float* __restrict__ S,
                                                       unsigned short* __restrict__ wtf,
                                                       float* __restrict__ dscale) {
    __shared__ float red[128];
    const int bx = blockIdx.x;
    const int tid = threadIdx.x;
    if (bx < 1728) {
        int idx = bx * 256 + tid;                  // 442368 total
        int e  = idx & 7;
        int l  = (idx >> 3) & 63;
        int c  = (idx >> 9) & 7;
        int ct = (idx >> 12) & 3;
        int ko = idx >> 14;
        int co = ct * 32 + (l & 31);
        int ci = c * 16 + (l >> 5) * 8 + e;
        wtf[idx] = f2bf(w[((size_t)co * CIN_ + ci) * 27 + ko]);
    } else {
        const int co = bx - 1728;
        const int ci = tid & 127;
        const float* wp = w + ((size_t)co * CIN_ + ci) * 27;
        float wsq = 0.f;
#pragma unroll
        for (int k = 0; k < 27; ++k) { float v = wp[k]; wsq += v * v; }
        for (int b = 0; b < B_; ++b) {
            float s = S[b * CIN_ + ci] + 1.0f;
            red[ci] = s * s * wsq;
            __syncthreads();
            for (int off = 64; off > 0; off >>= 1) {
                if (tid < off) red[tid] += red[tid + off];
                __syncthreads();
            }
            if (tid == 0) dscale[b * COUT_ + co] = rsqrtf(red[0] + EPSF);
            __syncthreads();
        }
    }
}

// ---------- x -> xT[b][z][x][c 8][y 32][ci 16] bf16, scaled by (S+1) ----------
__global__ __launch_bounds__(256) void xt_kernel(const float* __restrict__ x,
                                                 const float* __restrict__ S,
                                                 unsigned short* __restrict__ xT) {
    __shared__ float ls[128 * 33];
    const int xx = blockIdx.x, z = blockIdx.y, b = blockIdx.z;
    const int tid = threadIdx.x;
    const size_t base = (size_t)b * 4194304 + (size_t)z * 1024 + xx * 32;
#pragma unroll
    for (int it = 0; it < 4; ++it) {
        int i = tid + it * 256;
        int ci = i >> 3, y4 = (i & 7) * 4;
        float4 v = *(const float4*)(x + base + (size_t)ci * 32768 + y4);
        float s = S[b * CIN_ + ci] + 1.0f;
        ls[ci * 33 + y4 + 0] = v.x * s;
        ls[ci * 33 + y4 + 1] = v.y * s;
        ls[ci * 33 + y4 + 2] = v.z * s;
        ls[ci * 33 + y4 + 3] = v.w * s;
    }
    __syncthreads();
    const size_t obase = (size_t)((b * 32 + z) * 32 + xx) * 4096;
#pragma unroll
    for (int it = 0; it < 2; ++it) {
        int i = tid + it * 256;
        int y = i >> 4, c = (i >> 1) & 7, h = i & 1;
        ushort8 v;
#pragma unroll
        for (int j = 0; j < 8; ++j) v[j] = f2bf(ls[(c * 16 + h * 8 + j) * 33 + y]);
        *(ushort8*)(xT + obase + c * 512 + y * 16 + h * 8) = v;
    }
}

// One ky section: load 9 A-frags, then 6 zr rows x {4 bf reads, MFMA burst}.
template<int KY>
__device__ __forceinline__ void section(const char* buf, const char* abase,
                                        int aperlane, int bperlane, int xh2,
                                        f32x16 (&acc)[4][2]) {
    short8 a[9];
#pragma unroll
    for (int t = 0; t < 9; ++t)
        a[t] = *(const short8*)(abase + (t * 3 + KY) * 32768 + aperlane);
#pragma unroll
    for (int zr = 0; zr < 6; ++zr) {
        short8 bf[4];
#pragma unroll
        for (int xr = 0; xr < 4; ++xr)
            bf[xr] = *(const short8*)(buf + ((zr * 6 + xh2 + xr) * 68 + KY) * 16 + bperlane);
        __builtin_amdgcn_s_setprio(1);
#pragma unroll
        for (int cz = 0; cz < 4; ++cz) {
            const int kz = zr - cz;
            if (kz >= 0 && kz <= 2) {
#pragma unroll
                for (int cx = 0; cx < 2; ++cx)
#pragma unroll
                for (int kx = 0; kx < 3; ++kx)
                    acc[cz][cx] = __builtin_amdgcn_mfma_f32_32x32x16_bf16(
                        a[kz * 3 + kx], bf[cx + kx], acc[cz][cx], 0, 0, 0);
            }
        }
        __builtin_amdgcn_s_setprio(0);
    }
}

// ---------- main conv: implicit GEMM, bf16 MFMA 32x32x16 ----------
// grid (64 spatial, 4 b) = 256 blocks = 1/CU; block 512 = 8 waves (2/SIMD,
// SAME-block SIMD-mates). block tile: 128co x (4z,4x,32y)=512 pos.
// wave (cog, xh): 32co x (4z,2x,32y), acc[4][2]=128. STAGGER: xh=0 runs ky
// sections 0,1,2; xh=1 runs 2,1,0 -> SIMD-mates decorrelate stall windows.
__global__ __launch_bounds__(512, 1) void conv_mfma(const unsigned short* __restrict__ xT,
                                                    const unsigned short* __restrict__ wtf,
                                                    const float* __restrict__ dscale,
                                                    float* __restrict__ out) {
    __shared__ char smem[2][39168];                // 36 rows (6z x 6x) * 68 * 16B
    const int tid  = threadIdx.x;
    const int lane = tid & 63;
    const int wv   = tid >> 6;
    const int cog  = wv & 3;                       // SIMD id = wv&3 -> mates share cog
    const int xh2  = (wv >> 2) * 2;
    const int z0 = (blockIdx.x >> 3) * 4;
    const int x0 = (blockIdx.x & 7) * 4;
    const int b  = blockIdx.y;

    // ---- staging geometry: granule g = tid + s*512, g < 2448, dest g*16
    int goff[5];
    const int lbase = tid * 16;
#pragma unroll
    for (int s = 0; s < 5; ++s) {
        int g = tid + s * 512;
        goff[s] = -2;
        if (g < 2448) {
            int row = g / 68, rem = g - row * 68;
            int h = rem / 34, yi = rem - h * 34;
            int zi = row / 6, xi = row - zi * 6;
            int zg = z0 + zi - 1, xg = x0 + xi - 1;
            goff[s] = -1;                          // zero-fill
            if ((unsigned)zg < 32u && (unsigned)xg < 32u && yi >= 1 && yi <= 32)
                goff[s] = ((b * 32 + zg) * 32 + xg) * 8192 + (yi - 1) * 32 + h * 16;
        }
    }

    const char* xTb = (const char*)xT;
    const char* wtb = (const char*)wtf;
    const int bperlane = ((lane >> 5) * 34 + (lane & 31)) * 16;
    const int aperlane = lane * 16;

    f32x16 acc[4][2];
#pragma unroll
    for (int cz = 0; cz < 4; ++cz)
#pragma unroll
        for (int cx = 0; cx < 2; ++cx)
#pragma unroll
            for (int r = 0; r < 16; ++r) acc[cz][cx][r] = 0.f;

    // ---- prologue: stage chunk 0
    ushort8 st[5];
#pragma unroll
    for (int s = 0; s < 5; ++s) {
        ushort8 v = {0, 0, 0, 0, 0, 0, 0, 0};
        if (goff[s] >= 0) v = *(const ushort8*)(xTb + goff[s]);
        st[s] = v;
    }
#pragma unroll
    for (int s = 0; s < 5; ++s)
        if (goff[s] != -2) *(ushort8*)(&smem[0][0] + lbase + s * 8192) = st[s];
    __syncthreads();

    for (int c = 0; c < 8; ++c) {                  // ci chunks of 16
        if (c < 7) {                               // T14: issue next staging first
#pragma unroll
            for (int s = 0; s < 5; ++s) {
                ushort8 v = {0, 0, 0, 0, 0, 0, 0, 0};
                if (goff[s] >= 0) v = *(const ushort8*)(xTb + goff[s] + (c + 1) * 1024);
                st[s] = v;
            }
        }
        const char* buf   = smem[c & 1];
        const char* abase = wtb + c * 1024 + cog * 8192;

        if (xh2 == 0) {                            // stagger: opposite ky order
            section<0>(buf, abase, aperlane, bperlane, xh2, acc);
            section<1>(buf, abase, aperlane, bperlane, xh2, acc);
            section<2>(buf, abase, aperlane, bperlane, xh2, acc);
        } else {
            section<2>(buf, abase, aperlane, bperlane, xh2, acc);
            section<1>(buf, abase, aperlane, bperlane, xh2, acc);
            section<0>(buf, abase, aperlane, bperlane, xh2, acc);
        }

        if (c < 7) {
            char* nbuf = (char*)smem[(c + 1) & 1];
#pragma unroll
            for (int s = 0; s < 5; ++s)
                if (goff[s] != -2) *(ushort8*)(nbuf + lbase + s * 8192) = st[s];
        }
        __syncthreads();
    }

    // ---- epilogue: demodulate + store
    float dd[16];
#pragma unroll
    for (int r = 0; r < 16; ++r)
        dd[r] = dscale[b * COUT_ + cog * 32 + (r & 3) + 8 * (r >> 2) + 4 * (lane >> 5)];
#pragma unroll
    for (int cz = 0; cz < 4; ++cz)
#pragma unroll
    for (int cx = 0; cx < 2; ++cx) {
        size_t ob = (((size_t)(b * COUT_ + cog * 32) * 32 + (z0 + cz)) * 32 + (x0 + xh2 + cx)) * 32 + (lane & 31);
#pragma unroll
        for (int r = 0; r < 16; ++r) {
            int row = (r & 3) + 8 * (r >> 2) + 4 * (lane >> 5);
            out[ob + (size_t)row * 32768] = acc[cz][cx][r] * dd[r];
        }
    }
}

// ---------- round-1 fp32 fallback (used only if ws too small) ----------
__global__ __launch_bounds__(256, 4) void conv_kernel(const float* __restrict__ x,
                                                      const float* __restrict__ S,
                                                      const float* __restrict__ w,
                                                      const float* __restrict__ dscale,
                                                      float* __restrict__ out) {
    __shared__ float xs[6][6][36];
    __shared__ float wsm[27][16];
    const int tid = threadIdx.x;
    const int zt  = blockIdx.x >> 3;
    const int xt  = blockIdx.x & 7;
    const int co0 = blockIdx.y * 16;
    const int b   = blockIdx.z;
    const int z0 = zt * 4, x0 = xt * 4;
    const int lane = tid & 63;
    const int cg = tid >> 6;
    const int zz = (lane >> 4) & 3;
    const int xx = (lane >> 2) & 3;
    const int y0 = (lane & 3) * 8;
    float acc[4][8];
#pragma unroll
    for (int c = 0; c < 4; ++c)
#pragma unroll
        for (int j = 0; j < 8; ++j) acc[c][j] = 0.f;
    for (int ci = 0; ci < CIN_; ++ci) {
        __syncthreads();
        const float* xb = x + (size_t)(b * CIN_ + ci) * 32768;
        const float smod = S[b * CIN_ + ci] + 1.0f;
#pragma unroll
        for (int t = 0; t < 5; ++t) {
            int i = tid + t * 256;
            if (i < 6 * 6 * 34) {
                int zi = i / 204, r = i - zi * 204, xi = r / 34, yi = r - xi * 34;
                int z = z0 + zi - 1, xc = x0 + xi - 1, y = yi - 1;
                float v = 0.f;
                if ((unsigned)z < 32u && (unsigned)xc < 32u && (unsigned)y < 32u)
                    v = xb[z * 1024 + xc * 32 + y] * smod;
                xs[zi][xi][yi] = v;
            }
        }
#pragma unroll
        for (int t = 0; t < 2; ++t) {
            int i = tid + t * 256;
            if (i < 16 * 27) {
                int cog2 = i / 27, k = i - cog2 * 27;
                wsm[k][cog2] = w[((size_t)(co0 + cog2) * CIN_ + ci) * 27 + k];
            }
        }
        __syncthreads();
#pragma unroll
        for (int kz = 0; kz < 3; ++kz)
#pragma unroll
        for (int kx = 0; kx < 3; ++kx) {
            const float* xrow = &xs[zz + kz][xx + kx][y0];
            float xw[10];
#pragma unroll
            for (int q = 0; q < 10; ++q) xw[q] = xrow[q];
            const int kb = (kz * 3 + kx) * 3;
#pragma unroll
            for (int ky = 0; ky < 3; ++ky) {
                float4 wvv = *(const float4*)&wsm[kb + ky][cg * 4];
#pragma unroll
                for (int j = 0; j < 8; ++j) {
                    acc[0][j] = fmaf(xw[ky + j], wvv.x, acc[0][j]);
                    acc[1][j] = fmaf(xw[ky + j], wvv.y, acc[1][j]);
                    acc[2][j] = fmaf(xw[ky + j], wvv.z, acc[2][j]);
                    acc[3][j] = fmaf(xw[ky + j], wvv.w, acc[3][j]);
                }
            }
        }
    }
#pragma unroll
    for (int c = 0; c < 4; ++c) {
        const int co = co0 + cg * 4 + c;
        const float dd = dscale[b * COUT_ + co];
        float* ob = out + (((size_t)(b * COUT_ + co) * 32 + (z0 + zz)) * 32 + (x0 + xx)) * 32 + y0;
#pragma unroll
        for (int j = 0; j < 8; ++j) ob[j] = acc[c][j] * dd;
    }
}

extern "C" void kernel_launch(void* const* d_in, const int* in_sizes, int n_in,
                              void* d_out, int out_size, void* d_ws, size_t ws_size,
                              hipStream_t stream) {
    const float* x = (const float*)d_in[0];   // [4,128,32,32,32]
    const float* S = (const float*)d_in[1];   // [4,128]
    const float* w = (const float*)d_in[2];   // [128,128,3,3,3]
    float* out = (float*)d_out;

    const size_t NEED = 1048576 + 33554432;
    if (ws_size >= NEED) {
        float* dscale = (float*)d_ws;                                  // 2KB
        unsigned short* wtf = (unsigned short*)((char*)d_ws + 4096);   // 884736B
        unsigned short* xT  = (unsigned short*)((char*)d_ws + 1048576);
        wt_scale_kernel<<<dim3(1728 + 128), dim3(256), 0, stream>>>(w, S, wtf, dscale);
        xt_kernel<<<dim3(32, 32, 4), dim3(256), 0, stream>>>(x, S, xT);
        conv_mfma<<<dim3(64, 4), dim3(512), 0, stream>>>(xT, wtf, dscale, out);
    } else {
        float* dscale = (float*)d_ws;
        wt_scale_kernel<<<dim3(1856), dim3(256), 0, stream>>>(w, S, (unsigned short*)((char*)d_ws + 4096), dscale);
        conv_kernel<<<dim3(64, 8, 4), dim3(256), 0, stream>>>(x, S, w, dscale, out);
    }
}

// Round 12
// 111.321 us; speedup vs baseline: 1.0440x; 1.0440x over previous
//
#include <hip/hip_runtime.h>

#define B_    4
#define CIN_  128
#define COUT_ 128
#define EPSF  1e-8f

typedef short  short8  __attribute__((ext_vector_type(8)));
typedef unsigned short ushort8 __attribute__((ext_vector_type(8)));
typedef float  f32x16  __attribute__((ext_vector_type(16)));

__device__ __forceinline__ unsigned short f2bf(float f) {
    union { float f; unsigned int u; } v; v.f = f;
    unsigned int r = (v.u + 0x7fffu + ((v.u >> 16) & 1u)) >> 16;
    return (unsigned short)r;
}

// ---------- fused prep: xt transpose + weight transform + demod scales ----------
// blocks [0,4096):   x -> xT[b][z][x][c8][y32][ci16] bf16, scaled by (S+1)
// blocks [4096,5824): w -> wtf fragment order [ko27][cot4][cich8][lane64][e8]
// blocks [5824,5952): dscale[b][co] = rsqrt(sum_ci (S+1)^2 * sum_k w^2 + eps)
__global__ __launch_bounds__(256) void prep_kernel(const float* __restrict__ x,
                                                   const float* __restrict__ S,
                                                   const float* __restrict__ w,
                                                   unsigned short* __restrict__ xT,
                                                   unsigned short* __restrict__ wtf,
                                                   float* __restrict__ dscale) {
    __shared__ float ls[128 * 33];
    const int bx  = blockIdx.x;
    const int tid = threadIdx.x;

    if (bx < 4096) {
        const int xx = bx & 31, z = (bx >> 5) & 31, b = bx >> 10;
        const size_t base = (size_t)b * 4194304 + (size_t)z * 1024 + xx * 32;
#pragma unroll
        for (int it = 0; it < 4; ++it) {
            int i = tid + it * 256;                // 0..1023
            int ci = i >> 3, y4 = (i & 7) * 4;
            float4 v = *(const float4*)(x + base + (size_t)ci * 32768 + y4);
            float s = S[b * CIN_ + ci] + 1.0f;
            ls[ci * 33 + y4 + 0] = v.x * s;
            ls[ci * 33 + y4 + 1] = v.y * s;
            ls[ci * 33 + y4 + 2] = v.z * s;
            ls[ci * 33 + y4 + 3] = v.w * s;
        }
        __syncthreads();
        const size_t obase = (size_t)((b * 32 + z) * 32 + xx) * 4096;
#pragma unroll
        for (int it = 0; it < 2; ++it) {
            int i = tid + it * 256;                // 0..511
            int y = i >> 4, c = (i >> 1) & 7, h = i & 1;
            ushort8 v;
#pragma unroll
            for (int j = 0; j < 8; ++j) v[j] = f2bf(ls[(c * 16 + h * 8 + j) * 33 + y]);
            *(ushort8*)(xT + obase + c * 512 + y * 16 + h * 8) = v;
        }
    } else if (bx < 5824) {
        int idx = (bx - 4096) * 256 + tid;         // 442368 total
        int e  = idx & 7;
        int l  = (idx >> 3) & 63;
        int c  = (idx >> 9) & 7;
        int ct = (idx >> 12) & 3;
        int ko = idx >> 14;
        int co = ct * 32 + (l & 31);
        int ci = c * 16 + (l >> 5) * 8 + e;
        wtf[idx] = f2bf(w[((size_t)co * CIN_ + ci) * 27 + ko]);
    } else {
        const int co = bx - 5824;
        const int ci = tid & 127;
        const float* wp = w + ((size_t)co * CIN_ + ci) * 27;
        float wsq = 0.f;
#pragma unroll
        for (int k = 0; k < 27; ++k) { float v = wp[k]; wsq += v * v; }
        for (int b = 0; b < B_; ++b) {
            float s = S[b * CIN_ + ci] + 1.0f;
            ls[ci] = s * s * wsq;                  // tid and tid+128 write same value
            __syncthreads();
            for (int off = 64; off > 0; off >>= 1) {
                if (tid < off) ls[tid] += ls[tid + off];
                __syncthreads();
            }
            if (tid == 0) dscale[b * COUT_ + co] = rsqrtf(ls[0] + EPSF);
            __syncthreads();
        }
    }
}

// ---------- main conv: implicit GEMM, bf16 MFMA 32x32x16 (R3/R10 structure) ----------
// grid (128 spatial, 4 b); block 256 = 4 waves.
// block tile: co 128 (wave wv -> co wv*32..+31) x (4z,2x,32y)=256 positions.
// Each wave computes all 256 positions for its 32 co: acc[4 cz][2 cx] f32x16.
// LDS x-slab: 24 rows (6z x 4x halo) x [h2][y34][ci8] granule-16B planes.
//
// Measured plateau (R3..R11, 9 schedule variants): MfmaUtil 50+-3, conv ~101us.
// Structural: per-wave MFMA duty 46% x 2 waves/SIMD (256-reg tier); deeper
// per-wave batching, gload_lds, setprio, barrier phasing, stagger all null.
__global__ __launch_bounds__(256, 2) void conv_mfma(const unsigned short* __restrict__ xT,
                                                    const unsigned short* __restrict__ wtf,
                                                    const float* __restrict__ dscale,
                                                    float* __restrict__ out) {
    __shared__ char smem[2][26112];                // 24*68*16 B per buffer
    const int tid  = threadIdx.x;
    const int lane = tid & 63;
    const int wv   = tid >> 6;
    const int z0 = (blockIdx.x >> 4) * 4;
    const int x0 = (blockIdx.x & 15) * 2;
    const int b  = blockIdx.y;

    // ---- staging geometry: granule g = tid + s*256, g < 1632 ----
    int goff[7];
    const int lbase = tid * 16;
#pragma unroll
    for (int s = 0; s < 7; ++s) {
        int g = tid + s * 256;
        goff[s] = -2;                              // no slot
        if (g < 1632) {
            int row = g / 68, rem = g - row * 68;
            int h = rem / 34, yi = rem - h * 34;
            int zg = z0 + (row >> 2) - 1;
            int xg = x0 + (row & 3) - 1;
            goff[s] = -1;                          // zero-fill
            if ((unsigned)zg < 32u && (unsigned)xg < 32u && yi >= 1 && yi <= 32)
                goff[s] = ((b * 32 + zg) * 32 + xg) * 8192 + (yi - 1) * 32 + h * 16;
        }
    }

    const char* xTb = (const char*)xT;
    const char* wtb = (const char*)wtf;
    const int bperlane = ((lane >> 5) * 34 + (lane & 31)) * 16;   // plane + y pos
    const int aperlane = lane * 16;

    f32x16 acc[4][2];
#pragma unroll
    for (int cz = 0; cz < 4; ++cz)
#pragma unroll
        for (int cx = 0; cx < 2; ++cx)
#pragma unroll
            for (int r = 0; r < 16; ++r) acc[cz][cx][r] = 0.f;

    // ---- prologue: stage chunk 0 ----
    ushort8 st[7];
#pragma unroll
    for (int s = 0; s < 7; ++s) {
        ushort8 v = {0, 0, 0, 0, 0, 0, 0, 0};
        if (goff[s] >= 0) v = *(const ushort8*)(xTb + goff[s]);
        st[s] = v;
    }
#pragma unroll
    for (int s = 0; s < 7; ++s)
        if (goff[s] != -2) *(ushort8*)(&smem[0][0] + lbase + s * 4096) = st[s];
    __syncthreads();

    for (int c = 0; c < 8; ++c) {                  // ci chunks of 16
        // T14: issue next chunk's global loads early
        if (c < 7) {
#pragma unroll
            for (int s = 0; s < 7; ++s) {
                ushort8 v = {0, 0, 0, 0, 0, 0, 0, 0};
                if (goff[s] >= 0) v = *(const ushort8*)(xTb + goff[s] + (c + 1) * 1024);
                st[s] = v;
            }
        }
        const char* buf   = smem[c & 1];
        const char* abase = wtb + c * 1024 + wv * 8192;
#pragma unroll
        for (int ky = 0; ky < 3; ++ky) {
            short8 a[9];                           // A-frags for (kz,kx) at this ky
#pragma unroll
            for (int t = 0; t < 9; ++t)
                a[t] = *(const short8*)(abase + (t * 3 + ky) * 32768 + aperlane);
#pragma unroll
            for (int zr = 0; zr < 6; ++zr) {
                short8 bf[4];                      // input rows (zr, xr 0..3), y-shift ky
#pragma unroll
                for (int xr = 0; xr < 4; ++xr)
                    bf[xr] = *(const short8*)(buf + ((zr * 4 + xr) * 68 + ky) * 16 + bperlane);
#pragma unroll
                for (int cz = 0; cz < 4; ++cz) {
                    const int kz = zr - cz;
                    if (kz >= 0 && kz <= 2) {
#pragma unroll
                        for (int cx = 0; cx < 2; ++cx)
#pragma unroll
                        for (int kx = 0; kx < 3; ++kx)
                            acc[cz][cx] = __builtin_amdgcn_mfma_f32_32x32x16_bf16(
                                a[kz * 3 + kx], bf[cx + kx], acc[cz][cx], 0, 0, 0);
                    }
                }
            }
        }
        if (c < 7) {
            char* nbuf = (char*)smem[(c + 1) & 1];
#pragma unroll
            for (int s = 0; s < 7; ++s)
                if (goff[s] != -2) *(ushort8*)(nbuf + lbase + s * 4096) = st[s];
        }
        __syncthreads();
    }

    // ---- epilogue: demodulate + store ----
    float dd[16];
#pragma unroll
    for (int r = 0; r < 16; ++r)
        dd[r] = dscale[b * COUT_ + wv * 32 + (r & 3) + 8 * (r >> 2) + 4 * (lane >> 5)];
#pragma unroll
    for (int cz = 0; cz < 4; ++cz)
#pragma unroll
    for (int cx = 0; cx < 2; ++cx) {
        size_t ob = (((size_t)(b * COUT_ + wv * 32) * 32 + (z0 + cz)) * 32 + (x0 + cx)) * 32 + (lane & 31);
#pragma unroll
        for (int r = 0; r < 16; ++r) {
            int row = (r & 3) + 8 * (r >> 2) + 4 * (lane >> 5);
            out[ob + (size_t)row * 32768] = acc[cz][cx][r] * dd[r];
        }
    }
}

// ---------- fp32 fallback (used only if ws too small) ----------
__global__ __launch_bounds__(256, 4) void conv_kernel(const float* __restrict__ x,
                                                      const float* __restrict__ S,
                                                      const float* __restrict__ w,
                                                      const float* __restrict__ dscale,
                                                      float* __restrict__ out) {
    __shared__ float xs[6][6][36];
    __shared__ float wsm[27][16];
    const int tid = threadIdx.x;
    const int zt  = blockIdx.x >> 3;
    const int xt  = blockIdx.x & 7;
    const int co0 = blockIdx.y * 16;
    const int b   = blockIdx.z;
    const int z0 = zt * 4, x0 = xt * 4;
    const int lane = tid & 63;
    const int cg = tid >> 6;
    const int zz = (lane >> 4) & 3;
    const int xx = (lane >> 2) & 3;
    const int y0 = (lane & 3) * 8;
    float acc[4][8];
#pragma unroll
    for (int c = 0; c < 4; ++c)
#pragma unroll
        for (int j = 0; j < 8; ++j) acc[c][j] = 0.f;
    for (int ci = 0; ci < CIN_; ++ci) {
        __syncthreads();
        const float* xb = x + (size_t)(b * CIN_ + ci) * 32768;
        const float smod = S[b * CIN_ + ci] + 1.0f;
#pragma unroll
        for (int t = 0; t < 5; ++t) {
            int i = tid + t * 256;
            if (i < 6 * 6 * 34) {
                int zi = i / 204, r = i - zi * 204, xi = r / 34, yi = r - xi * 34;
                int z = z0 + zi - 1, xc = x0 + xi - 1, y = yi - 1;
                float v = 0.f;
                if ((unsigned)z < 32u && (unsigned)xc < 32u && (unsigned)y < 32u)
                    v = xb[z * 1024 + xc * 32 + y] * smod;
                xs[zi][xi][yi] = v;
            }
        }
#pragma unroll
        for (int t = 0; t < 2; ++t) {
            int i = tid + t * 256;
            if (i < 16 * 27) {
                int cog2 = i / 27, k = i - cog2 * 27;
                wsm[k][cog2] = w[((size_t)(co0 + cog2) * CIN_ + ci) * 27 + k];
            }
        }
        __syncthreads();
#pragma unroll
        for (int kz = 0; kz < 3; ++kz)
#pragma unroll
        for (int kx = 0; kx < 3; ++kx) {
            const float* xrow = &xs[zz + kz][xx + kx][y0];
            float xw[10];
#pragma unroll
            for (int q = 0; q < 10; ++q) xw[q] = xrow[q];
            const int kb = (kz * 3 + kx) * 3;
#pragma unroll
            for (int ky = 0; ky < 3; ++ky) {
                float4 wvv = *(const float4*)&wsm[kb + ky][cg * 4];
#pragma unroll
                for (int j = 0; j < 8; ++j) {
                    acc[0][j] = fmaf(xw[ky + j], wvv.x, acc[0][j]);
                    acc[1][j] = fmaf(xw[ky + j], wvv.y, acc[1][j]);
                    acc[2][j] = fmaf(xw[ky + j], wvv.z, acc[2][j]);
                    acc[3][j] = fmaf(xw[ky + j], wvv.w, acc[3][j]);
                }
            }
        }
    }
#pragma unroll
    for (int c = 0; c < 4; ++c) {
        const int co = co0 + cg * 4 + c;
        const float dd = dscale[b * COUT_ + co];
        float* ob = out + (((size_t)(b * COUT_ + co) * 32 + (z0 + zz)) * 32 + (x0 + xx)) * 32 + y0;
#pragma unroll
        for (int j = 0; j < 8; ++j) ob[j] = acc[c][j] * dd;
    }
}

__global__ __launch_bounds__(128) void scale_only_kernel(const float* __restrict__ S,
                                                         const float* __restrict__ w,
                                                         float* __restrict__ d) {
    const int co = blockIdx.x;
    const int ci = threadIdx.x;
    const float* wp = w + ((size_t)co * CIN_ + ci) * 27;
    float wsq = 0.f;
#pragma unroll
    for (int k = 0; k < 27; ++k) { float v = wp[k]; wsq += v * v; }
    __shared__ float red[128];
    for (int b = 0; b < B_; ++b) {
        float s = S[b * CIN_ + ci] + 1.0f;
        red[ci] = s * s * wsq;
        __syncthreads();
        for (int off = 64; off > 0; off >>= 1) {
            if (ci < off) red[ci] += red[ci + off];
            __syncthreads();
        }
        if (ci == 0) d[b * COUT_ + co] = rsqrtf(red[0] + EPSF);
        __syncthreads();
    }
}

extern "C" void kernel_launch(void* const* d_in, const int* in_sizes, int n_in,
                              void* d_out, int out_size, void* d_ws, size_t ws_size,
                              hipStream_t stream) {
    const float* x = (const float*)d_in[0];   // [4,128,32,32,32]
    const float* S = (const float*)d_in[1];   // [4,128]
    const float* w = (const float*)d_in[2];   // [128,128,3,3,3]
    float* out = (float*)d_out;

    const size_t NEED = 1048576 + 33554432;
    if (ws_size >= NEED) {
        float* dscale = (float*)d_ws;                                  // 2KB
        unsigned short* wtf = (unsigned short*)((char*)d_ws + 4096);   // 884736B
        unsigned short* xT  = (unsigned short*)((char*)d_ws + 1048576);
        prep_kernel<<<dim3(5952), dim3(256), 0, stream>>>(x, S, w, xT, wtf, dscale);
        conv_mfma<<<dim3(128, 4), dim3(256), 0, stream>>>(xT, wtf, dscale, out);
    } else {
        float* dscale = (float*)d_ws;
        scale_only_kernel<<<dim3(COUT_), dim3(128), 0, stream>>>(S, w, dscale);
        conv_kernel<<<dim3(64, 8, 4), dim3(256), 0, stream>>>(x, S, w, dscale, out);
    }
}